// Round 16
// baseline (33.115 us; speedup 1.0000x reference)
//
#include <hip/hip_runtime.h>
#include <math.h>

// MPDO chain via QUAD fp8-delta table + K=64 scaled MFMA, fully unrolled.
//   per b: edge = Pi_t M_t (64x64); out = log(tr(edge))
//
// Step-cost invariance (R3-R15): ~1650 cyc/step regardless of per-step
// compute/bytes/ILP; only STEP COUNT scales. R16: quad tier in fp8-delta
// (16 MB, L3-resident; R7's failure was 32MB bf16 + rolled loop), 16 steps.
//   prep2both: bf16 (1/16)P^T and (1/16)P pair tables (R7-verified).
//   prep3q: Q/256 = (Pe/16)(Po/16) via bf16 MFMA (R7-verified product),
//           subtract I on C-layout diagonal, pack PACK4+permlane32_swap
//           (R15 relayout) into K=64 fp8 A-frag(D_q^T). 4KB/entry.
//   main: R15 structure, 16 steps, 8-bit combos via 8 ballots + SALU.
// X <- X + D_q^T X per step (identity exact in f32 C-operand).
// Scale (1/256)^16 = 4^-64 -> log += 64*ln4.
// Fallback: ws < 24MB -> verified fp32 VALU kernel.

#define NSITES 64
#define NPAIRS 32
#define NQUADS 16

typedef short  s16x8  __attribute__((ext_vector_type(8)));
typedef float  f32x16 __attribute__((ext_vector_type(16)));
typedef int    i32x8  __attribute__((ext_vector_type(8)));

union Frag  { unsigned int u[4]; s16x8 v; uint4 q; };
union AFrag { uint4 q[2]; i32x8 v; };

// pack 4 f32 -> 1 dword of 4 fp8 e4m3
#define PACK4(P, A0, A1, A2, A3)                                               \
    asm("v_cvt_pk_fp8_f32 %0, %1, %2" : "=v"(P) : "v"(A0), "v"(A1));           \
    asm("v_cvt_pk_fp8_f32 %0, %1, %2 op_sel:[0,0,1]" : "+v"(P) : "v"(A2), "v"(A3));

#define MFMA64(A, B, C)                                                        \
    __builtin_amdgcn_mfma_scale_f32_32x32x64_f8f6f4(                           \
        (A), (B), (C), 0, 0, 0, 0x7F7F7F7F, 0, 0x7F7F7F7F)

// ---------- prep2both: bf16 (1/16)P^T and (1/16)P (verified R7) ----------
__global__ __launch_bounds__(64)
void mpdo_prep2both(const float* __restrict__ T, uint4* __restrict__ MfpT,
                    uint4* __restrict__ MfpN) {
    const int blk = blockIdx.x;              // 32 pairs * 16 combos
    const int pair = blk >> 4, combo = blk & 15;
    const int c0 = combo >> 2, c1 = combo & 3;
    const int ir0 = c0 >> 1, ic0 = c0 & 1, ir1 = c1 >> 1, ic1 = c1 & 1;
    const int lane = threadIdx.x;
    const int site0 = 2 * pair, site1 = 2 * pair + 1;

    __shared__ float sT0[256], sT1[256], sT2[256], sT3[256];
    __shared__ float sPA[16 * 64], sPB[16 * 64];

    *(float4*)&sT0[lane * 4] = *(const float4*)(T + ((size_t)(site0 * 2 + ir0)) * 256 + lane * 4);
    *(float4*)&sT1[lane * 4] = *(const float4*)(T + ((size_t)(site0 * 2 + ic0)) * 256 + lane * 4);
    *(float4*)&sT2[lane * 4] = *(const float4*)(T + ((size_t)(site1 * 2 + ir1)) * 256 + lane * 4);
    *(float4*)&sT3[lane * 4] = *(const float4*)(T + ((size_t)(site1 * 2 + ic1)) * 256 + lane * 4);
    __syncthreads();

    {
        const int i = lane >> 3, j = lane & 7;
        float pa[4][4], pb[4][4];
#pragma unroll
        for (int k = 0; k < 4; ++k)
#pragma unroll
            for (int jp = 0; jp < 4; ++jp) { pa[k][jp] = 0.0f; pb[k][jp] = 0.0f; }
#pragma unroll
        for (int a = 0; a < 8; ++a) {
            float4 x0 = *(const float4*)&sT0[(i * 8 + a) * 4];
            float4 y0 = *(const float4*)&sT2[(a * 8 + j) * 4];
            float4 x1 = *(const float4*)&sT1[(i * 8 + a) * 4];
            float4 y1 = *(const float4*)&sT3[(a * 8 + j) * 4];
            const float xk0[4] = {x0.x, x0.y, x0.z, x0.w};
            const float yj0[4] = {y0.x, y0.y, y0.z, y0.w};
            const float xk1[4] = {x1.x, x1.y, x1.z, x1.w};
            const float yj1[4] = {y1.x, y1.y, y1.z, y1.w};
#pragma unroll
            for (int k = 0; k < 4; ++k)
#pragma unroll
                for (int jp = 0; jp < 4; ++jp) {
                    pa[k][jp] = fmaf(xk0[k], yj0[jp], pa[k][jp]);
                    pb[k][jp] = fmaf(xk1[k], yj1[jp], pb[k][jp]);
                }
        }
#pragma unroll
        for (int k = 0; k < 4; ++k)
#pragma unroll
            for (int jp = 0; jp < 4; ++jp) {
                sPA[(k * 4 + jp) * 64 + lane] = pa[k][jp];
                sPB[(k * 4 + jp) * 64 + lane] = pb[k][jp];
            }
    }
    __syncthreads();

    const int h = lane >> 5, r = lane & 31, m = r & 7, j2 = r >> 3;

    {   // ---- (1/16)P^T table ----
        float acc[8][8];
#pragma unroll
        for (int f = 0; f < 8; ++f)
#pragma unroll
            for (int e = 0; e < 8; ++e) acc[f][e] = 0.0f;
#pragma unroll 4
        for (int c = 0; c < 16; ++c) {
            float paf[8], pbe[8];
#pragma unroll
            for (int ti = 0; ti < 2; ++ti)
#pragma unroll
                for (int kt = 0; kt < 4; ++kt)
                    paf[ti * 4 + kt] = sPA[c * 64 + (2 * kt + h) * 8 + (4 * ti + j2)];
#pragma unroll
            for (int e = 0; e < 8; ++e) pbe[e] = sPB[c * 64 + e * 8 + m];
#pragma unroll
            for (int f = 0; f < 8; ++f)
#pragma unroll
                for (int e = 0; e < 8; ++e)
                    acc[f][e] = fmaf(paf[f], pbe[e], acc[f][e]);
        }
#pragma unroll
        for (int f = 0; f < 8; ++f) {
            unsigned int wds[4];
#pragma unroll
            for (int q = 0; q < 4; ++q) {
                float v0 = acc[f][2 * q]     * 0.0625f;
                float v1 = acc[f][2 * q + 1] * 0.0625f;
                asm("v_cvt_pk_bf16_f32 %0, %1, %2" : "=v"(wds[q]) : "v"(v0), "v"(v1));
            }
            MfpT[((size_t)(pair * 16 + combo) * 8 + f) * 64 + lane] =
                make_uint4(wds[0], wds[1], wds[2], wds[3]);
        }
    }

    {   // ---- (1/16)P (non-transposed) table ----
        float acc[8][8];
#pragma unroll
        for (int f = 0; f < 8; ++f)
#pragma unroll
            for (int e = 0; e < 8; ++e) acc[f][e] = 0.0f;
#pragma unroll 4
        for (int c = 0; c < 16; ++c) {
            float paf[8], pbe[8];
#pragma unroll
            for (int ti = 0; ti < 2; ++ti)
#pragma unroll
                for (int kt = 0; kt < 4; ++kt)
                    paf[ti * 4 + kt] = sPA[c * 64 + (4 * ti + j2) * 8 + (2 * kt + h)];
#pragma unroll
            for (int e = 0; e < 8; ++e) pbe[e] = sPB[c * 64 + m * 8 + e];
#pragma unroll
            for (int f = 0; f < 8; ++f)
#pragma unroll
                for (int e = 0; e < 8; ++e)
                    acc[f][e] = fmaf(paf[f], pbe[e], acc[f][e]);
        }
#pragma unroll
        for (int f = 0; f < 8; ++f) {
            unsigned int wds[4];
#pragma unroll
            for (int q = 0; q < 4; ++q) {
                float v0 = acc[f][2 * q]     * 0.0625f;
                float v1 = acc[f][2 * q + 1] * 0.0625f;
                asm("v_cvt_pk_bf16_f32 %0, %1, %2" : "=v"(wds[q]) : "v"(v0), "v"(v1));
            }
            MfpN[((size_t)(pair * 16 + combo) * 8 + f) * 64 + lane] =
                make_uint4(wds[0], wds[1], wds[2], wds[3]);
        }
    }
}

// ---------- prep3q: fp8 K=64 A-frag of D_q^T = Q/256 - I ----------
__global__ __launch_bounds__(64)
void mpdo_prep3q(const uint4* __restrict__ MfpT, const uint4* __restrict__ MfpN,
                 uint4* __restrict__ Mfq8) {
    const int blk = blockIdx.x;              // u*256 + ce*16 + co
    const int u = blk >> 8, ce = (blk >> 4) & 15, co = blk & 15;
    const int lane = threadIdx.x;
    const int pe = 2 * u, po = 2 * u + 1;
    const int col = lane & 31, hh = lane >> 5;

    // A = A-frag((1/16)P_e) bf16; B-slot fed A-frag((1/16)P_o^T) => B-eff = P_o/16
    Frag Ae[2][4], Bo[4][2];
    const uint4* abase = MfpN + ((size_t)(pe * 16 + ce)) * 8 * 64 + lane;
#pragma unroll
    for (int ti = 0; ti < 2; ++ti)
#pragma unroll
        for (int kt = 0; kt < 4; ++kt)
            Ae[ti][kt].q = abase[(ti * 4 + kt) * 64];
    const uint4* bbase = MfpT + ((size_t)(po * 16 + co)) * 8 * 64 + lane;
#pragma unroll
    for (int kt = 0; kt < 4; ++kt)
#pragma unroll
        for (int tj = 0; tj < 2; ++tj)
            Bo[kt][tj].q = bbase[(tj * 4 + kt) * 64];

    f32x16 acc[2][2];   // Q/256 in C-layout
#pragma unroll
    for (int ti = 0; ti < 2; ++ti)
#pragma unroll
        for (int tj = 0; tj < 2; ++tj) {
            f32x16 d = {};
#pragma unroll
            for (int kt = 0; kt < 4; ++kt)
                d = __builtin_amdgcn_mfma_f32_32x32x16_bf16(Ae[ti][kt].v, Bo[kt][tj].v, d, 0, 0, 0);
            acc[ti][tj] = d;
        }

    // subtract identity on the C-layout diagonal
#pragma unroll
    for (int tt = 0; tt < 2; ++tt)
#pragma unroll
        for (int g = 0; g < 16; ++g) {
            int row = (g & 3) + 8 * (g >> 2) + 4 * hh;
            if (row == col) acc[tt][tt][g] -= 1.0f;
        }

    // pack to fp8 K=64 A-frag(D_q^T): column-block ct -> frags (ct*2+half)
#pragma unroll
    for (int ct = 0; ct < 2; ++ct) {
        unsigned dw[8];
#pragma unroll
        for (int q = 0; q < 4; ++q) {
            unsigned p0, p1;
            PACK4(p0, acc[0][ct][4 * q + 0], acc[0][ct][4 * q + 1],
                      acc[0][ct][4 * q + 2], acc[0][ct][4 * q + 3])
            PACK4(p1, acc[1][ct][4 * q + 0], acc[1][ct][4 * q + 1],
                      acc[1][ct][4 * q + 2], acc[1][ct][4 * q + 3])
            asm("v_permlane32_swap_b32 %0, %1" : "+v"(p0), "+v"(p1));
            dw[2 * q] = p0; dw[2 * q + 1] = p1;
        }
        Mfq8[((size_t)blk * 4 + ct * 2 + 0) * 64 + lane] =
            make_uint4(dw[0], dw[1], dw[2], dw[3]);
        Mfq8[((size_t)blk * 4 + ct * 2 + 1) * 64 + lane] =
            make_uint4(dw[4], dw[5], dw[6], dw[7]);
    }
}

// ---------- main: 1 wave/b, 16 quad-steps fully unrolled, 4 K=64 MFMA/step ----------
__global__ __launch_bounds__(64, 1)
void mpdo_mfmaQ8(const int* __restrict__ qn, const uint4* __restrict__ Mfq8,
                 float* __restrict__ out) {
    const int b = blockIdx.x;
    const int lane = threadIdx.x;
    const int* qb = qn + (size_t)b * (2 * NSITES);
    // lane u (=lane&15) holds 8-bit combo of quad u (sites 4u..4u+3)
    const int u = lane & 15, s = 4 * u;
    const int qq = (qb[s] << 7) | (qb[64 + s] << 6) | (qb[s + 1] << 5) | (qb[64 + s + 1] << 4) |
                   (qb[s + 2] << 3) | (qb[64 + s + 2] << 2) | (qb[s + 3] << 1) | qb[64 + s + 3];
    const unsigned long long m7 = __ballot(qq & 128), m6 = __ballot(qq & 64);
    const unsigned long long m5 = __ballot(qq & 32),  m4 = __ballot(qq & 16);
    const unsigned long long m3 = __ballot(qq & 8),   m2 = __ballot(qq & 4);
    const unsigned long long m1 = __ballot(qq & 2),   m0 = __ballot(qq & 1);
    const int col = lane & 31, hh = lane >> 5;
    const int laneoff = lane * 16;

    f32x16 acc[2][2];   // X, C-layout
#pragma unroll
    for (int rt = 0; rt < 2; ++rt)
#pragma unroll
        for (int ct = 0; ct < 2; ++ct)
#pragma unroll
            for (int g = 0; g < 16; ++g) {
                int row = (g & 3) + 8 * (g >> 2) + 4 * hh;
                acc[rt][ct][g] = (rt == ct && row == col) ? 1.0f : 0.0f;
            }

    const char* Mbase = (const char*)Mfq8;
    AFrag A0[2], A1[2], A2[2];

#define COMBO8(T_) ((int)(((((m7) >> (T_)) & 1ull) << 7) | ((((m6) >> (T_)) & 1ull) << 6) | \
                          ((((m5) >> (T_)) & 1ull) << 5) | ((((m4) >> (T_)) & 1ull) << 4) | \
                          ((((m3) >> (T_)) & 1ull) << 3) | ((((m2) >> (T_)) & 1ull) << 2) | \
                          ((((m1) >> (T_)) & 1ull) << 1) | (((m0) >> (T_)) & 1ull)))
#define LOADF(DST, QIDX)                                                       \
    {                                                                          \
        int c_ = COMBO8(QIDX);                                                 \
        const char* nb_ = Mbase + (((size_t)(QIDX) * 256 + c_) << 12) + laneoff;\
        DST[0].q[0] = *(const uint4*)(nb_ + 0 * 1024);                         \
        DST[0].q[1] = *(const uint4*)(nb_ + 1 * 1024);                         \
        DST[1].q[0] = *(const uint4*)(nb_ + 2 * 1024);                         \
        DST[1].q[1] = *(const uint4*)(nb_ + 3 * 1024);                         \
    }

#define MAKE_BCOL(BV, CT)                                                      \
    {                                                                          \
        _Pragma("unroll")                                                      \
        for (int q = 0; q < 4; ++q) {                                          \
            unsigned p0, p1;                                                   \
            PACK4(p0, acc[0][CT][4 * q + 0], acc[0][CT][4 * q + 1],            \
                      acc[0][CT][4 * q + 2], acc[0][CT][4 * q + 3])            \
            PACK4(p1, acc[1][CT][4 * q + 0], acc[1][CT][4 * q + 1],            \
                      acc[1][CT][4 * q + 2], acc[1][CT][4 * q + 3])            \
            asm("v_permlane32_swap_b32 %0, %1" : "+v"(p0), "+v"(p1));          \
            BV[2 * q] = (int)p0; BV[2 * q + 1] = (int)p1;                      \
        }                                                                      \
    }

#define SITE_BODY(T_, CUR, NXT)                                                \
    {                                                                          \
        if ((T_) + 2 < 16) { LOADF(NXT, (T_) + 2) }                            \
        i32x8 b0, b1;                                                          \
        MAKE_BCOL(b0, 0)                                                       \
        MAKE_BCOL(b1, 1)                                                       \
        acc[0][0] = MFMA64(CUR[0].v, b0, acc[0][0]);                           \
        acc[0][1] = MFMA64(CUR[0].v, b1, acc[0][1]);                           \
        acc[1][0] = MFMA64(CUR[1].v, b0, acc[1][0]);                           \
        acc[1][1] = MFMA64(CUR[1].v, b1, acc[1][1]);                           \
    }

    LOADF(A0, 0)
    LOADF(A1, 1)

    SITE_BODY(0,  A0, A2) SITE_BODY(1,  A1, A0) SITE_BODY(2,  A2, A1)
    SITE_BODY(3,  A0, A2) SITE_BODY(4,  A1, A0) SITE_BODY(5,  A2, A1)
    SITE_BODY(6,  A0, A2) SITE_BODY(7,  A1, A0) SITE_BODY(8,  A2, A1)
    SITE_BODY(9,  A0, A2) SITE_BODY(10, A1, A0) SITE_BODY(11, A2, A1)
    SITE_BODY(12, A0, A2) SITE_BODY(13, A1, A0) SITE_BODY(14, A2, A1)
    SITE_BODY(15, A0, A2)
#undef SITE_BODY
#undef MAKE_BCOL
#undef LOADF
#undef COMBO8

    // trace (X = full product transposed; trace invariant)
    float diag = 0.0f;
#pragma unroll
    for (int tt = 0; tt < 2; ++tt)
#pragma unroll
        for (int g = 0; g < 16; ++g) {
            int row = (g & 3) + 8 * (g >> 2) + 4 * hh;
            if (row == col) diag += acc[tt][tt][g];
        }
#pragma unroll
    for (int off = 32; off >= 1; off >>= 1)
        diag += __shfl_xor(diag, off, 64);

    if (lane == 0) {
        float tr = diag;
        float re = logf(fabsf(tr)) + 64.0f * 1.3862943611198906f;  // undo 4^-64
        float im = (tr < 0.0f) ? 3.14159265358979323846f : 0.0f;
        out[2 * b]     = re;
        out[2 * b + 1] = im;
    }
}

// ---------- fallback fp32 VALU kernel (verified R2) ----------
#define DD 8
#define KCHI 4
__global__ __launch_bounds__(64, 1)
void mpdo_chain(const int* __restrict__ qn, const float* __restrict__ T,
                float* __restrict__ out) {
    const int b = blockIdx.x;
    const int lane = threadIdx.x;
    __shared__ float sA[KCHI][DD][DD];
    __shared__ float sB[KCHI][DD][DD];
    float E[DD][DD];
#pragma unroll
    for (int i = 0; i < DD; ++i)
#pragma unroll
        for (int l = 0; l < DD; ++l) E[i][l] = (i * DD + l == lane) ? 1.0f : 0.0f;
    const int* qb = qn + (size_t)b * (2 * NSITES);
    int ir0 = qb[0], ic0 = qb[NSITES];
    float4 aP = *reinterpret_cast<const float4*>(T + (size_t)ir0 * 256 + lane * 4);
    float4 bP = *reinterpret_cast<const float4*>(T + (size_t)ic0 * 256 + lane * 4);
    const int li = lane >> 3, lj = lane & 7;
#pragma unroll 1
    for (int site = 0; site < NSITES; ++site) {
        __syncthreads();
        sA[0][li][lj] = 0.5f * aP.x; sA[1][li][lj] = 0.5f * aP.y;
        sA[2][li][lj] = 0.5f * aP.z; sA[3][li][lj] = 0.5f * aP.w;
        sB[0][li][lj] = 0.5f * bP.x; sB[1][li][lj] = 0.5f * bP.y;
        sB[2][li][lj] = 0.5f * bP.z; sB[3][li][lj] = 0.5f * bP.w;
        __syncthreads();
        if (site + 1 < NSITES) {
            int irn = qb[site + 1], icn = qb[NSITES + site + 1];
            aP = *reinterpret_cast<const float4*>(T + ((size_t)(site + 1) * 2 + irn) * 256 + lane * 4);
            bP = *reinterpret_cast<const float4*>(T + ((size_t)(site + 1) * 2 + icn) * 256 + lane * 4);
        }
        float Ep[DD][DD];
#pragma unroll
        for (int j = 0; j < DD; ++j)
#pragma unroll
            for (int m = 0; m < DD; ++m) Ep[j][m] = 0.0f;
#pragma unroll 1
        for (int k = 0; k < KCHI; ++k) {
            float tmp[DD][DD];
#pragma unroll
            for (int l = 0; l < DD; ++l) {
                const float4* bp = reinterpret_cast<const float4*>(&sB[k][l][0]);
                float4 b0 = bp[0], b1 = bp[1];
                float brow[DD] = {b0.x, b0.y, b0.z, b0.w, b1.x, b1.y, b1.z, b1.w};
                if (l == 0) {
#pragma unroll
                    for (int i = 0; i < DD; ++i)
#pragma unroll
                        for (int m = 0; m < DD; ++m) tmp[i][m] = E[i][0] * brow[m];
                } else {
#pragma unroll
                    for (int i = 0; i < DD; ++i)
#pragma unroll
                        for (int m = 0; m < DD; ++m)
                            tmp[i][m] = fmaf(E[i][l], brow[m], tmp[i][m]);
                }
            }
#pragma unroll
            for (int i = 0; i < DD; ++i) {
                const float4* ap = reinterpret_cast<const float4*>(&sA[k][i][0]);
                float4 a0 = ap[0], a1 = ap[1];
                float arow[DD] = {a0.x, a0.y, a0.z, a0.w, a1.x, a1.y, a1.z, a1.w};
#pragma unroll
                for (int j = 0; j < DD; ++j)
#pragma unroll
                    for (int m = 0; m < DD; ++m)
                        Ep[j][m] = fmaf(arow[j], tmp[i][m], Ep[j][m]);
            }
        }
#pragma unroll
        for (int i = 0; i < DD; ++i)
#pragma unroll
            for (int l = 0; l < DD; ++l) E[i][l] = Ep[i][l];
    }
    float diag = 0.0f;
#pragma unroll
    for (int i = 0; i < DD; ++i)
#pragma unroll
        for (int l = 0; l < DD; ++l) diag += (i * DD + l == lane) ? E[i][l] : 0.0f;
#pragma unroll
    for (int off = 32; off >= 1; off >>= 1) diag += __shfl_xor(diag, off, 64);
    if (lane == 0) {
        float tr = diag;
        out[2 * b]     = logf(fabsf(tr)) + 64.0f * 1.3862943611198906f;
        out[2 * b + 1] = (tr < 0.0f) ? 3.14159265358979323846f : 0.0f;
    }
}

extern "C" void kernel_launch(void* const* d_in, const int* in_sizes, int n_in,
                              void* d_out, int out_size, void* d_ws, size_t ws_size,
                              hipStream_t stream) {
    const int*   qn  = (const int*)d_in[0];
    const float* T   = (const float*)d_in[1];
    float*       out = (float*)d_out;
    const int B = in_sizes[0] / (2 * NSITES);
    const size_t SZ_PAIR = (size_t)NPAIRS * 16 * 8 * 64 * 16;    // 4 MB per bf16 table
    const size_t SZ_QUAD = (size_t)NQUADS * 256 * 4 * 64 * 16;   // 16 MB fp8 quad
    if (ws_size >= 2 * SZ_PAIR + SZ_QUAD) {
        uint4* MfpT = (uint4*)d_ws;
        uint4* MfpN = (uint4*)((char*)d_ws + SZ_PAIR);
        uint4* Mfq8 = (uint4*)((char*)d_ws + 2 * SZ_PAIR);
        mpdo_prep2both<<<dim3(NPAIRS * 16), dim3(64), 0, stream>>>(T, MfpT, MfpN);
        mpdo_prep3q<<<dim3(NQUADS * 256), dim3(64), 0, stream>>>(MfpT, MfpN, Mfq8);
        mpdo_mfmaQ8<<<dim3(B), dim3(64), 0, stream>>>(qn, Mfq8, out);
    } else {
        mpdo_chain<<<dim3(B), dim3(64), 0, stream>>>(qn, T, out);
    }
}

// Round 17
// 25.791 us; speedup vs baseline: 1.2840x; 1.2840x over previous
//
#include <hip/hip_runtime.h>
#include <math.h>

// MPDO chain: fp8 DELTA pair table + K=64 scaled MFMA + dual chain, unrolled.
//   per b: edge = Pi_t M_t (64x64); out = log(tr(edge))
//
// Law (R3-R16): table must be L2-resident (pair tier); only step count and
// unroll helped. R13 (dual chain) was ROLLED - confounded by the factor R14
// fixed (+2.4us from unroll alone). R17 = dual chain + full unroll + slim
// R15 step (4 K=64 MFMA, fits 512-VGPR budget at 1 wave/SIMD):
//   chain0 = pairs 0..15 -> acc0, chain1 = pairs 16..31 -> acc1,
//   steps interleaved 1:1 in straight-line code -> chain1's independent
//   MFMAs/cvts fill chain0's dependency stalls.
// Epilogue (R13-verified): tr(G0 G1) = sum G0^T[p,q] G1^T[q,p] via padded LDS.
// fp8-delta step (R11/R15-verified): X <- X + D^T X, identity exact in f32 C.
// Scale 4^-64 -> log += 64*ln4.
// Fallback: ws < 2MB -> verified fp32 VALU kernel.

#define NSITES 64
#define NPAIRS 32

typedef float f32x16 __attribute__((ext_vector_type(16)));
typedef int   i32x8  __attribute__((ext_vector_type(8)));

union AFrag { uint4 q[2]; i32x8 v; };

// pack 4 f32 -> 1 dword of 4 fp8 e4m3
#define PACK4(P, A0, A1, A2, A3)                                               \
    asm("v_cvt_pk_fp8_f32 %0, %1, %2" : "=v"(P) : "v"(A0), "v"(A1));           \
    asm("v_cvt_pk_fp8_f32 %0, %1, %2 op_sel:[0,0,1]" : "+v"(P) : "v"(A2), "v"(A3));

#define MFMA64(A, B, C)                                                        \
    __builtin_amdgcn_mfma_scale_f32_32x32x64_f8f6f4(                           \
        (A), (B), (C), 0, 0, 0, 0x7F7F7F7F, 0, 0x7F7F7F7F)

// ---------- prep2f8k: D^T = (1/16)P^T - I in fp8, K=64 A-frag (R15-verified) ----------
__global__ __launch_bounds__(64)
void mpdo_prep2f8k(const float* __restrict__ T, uint4* __restrict__ Mf8) {
    const int blk = blockIdx.x;              // 32 pairs * 16 combos
    const int pair = blk >> 4, combo = blk & 15;
    const int c0 = combo >> 2, c1 = combo & 3;
    const int ir0 = c0 >> 1, ic0 = c0 & 1, ir1 = c1 >> 1, ic1 = c1 & 1;
    const int lane = threadIdx.x;
    const int site0 = 2 * pair, site1 = 2 * pair + 1;

    __shared__ float sT0[256], sT1[256], sT2[256], sT3[256];
    __shared__ float sPA[16 * 64], sPB[16 * 64];

    *(float4*)&sT0[lane * 4] = *(const float4*)(T + ((size_t)(site0 * 2 + ir0)) * 256 + lane * 4);
    *(float4*)&sT1[lane * 4] = *(const float4*)(T + ((size_t)(site0 * 2 + ic0)) * 256 + lane * 4);
    *(float4*)&sT2[lane * 4] = *(const float4*)(T + ((size_t)(site1 * 2 + ir1)) * 256 + lane * 4);
    *(float4*)&sT3[lane * 4] = *(const float4*)(T + ((size_t)(site1 * 2 + ic1)) * 256 + lane * 4);
    __syncthreads();

    {
        const int i = lane >> 3, j = lane & 7;
        float pa[4][4], pb[4][4];
#pragma unroll
        for (int k = 0; k < 4; ++k)
#pragma unroll
            for (int jp = 0; jp < 4; ++jp) { pa[k][jp] = 0.0f; pb[k][jp] = 0.0f; }
#pragma unroll
        for (int a = 0; a < 8; ++a) {
            float4 x0 = *(const float4*)&sT0[(i * 8 + a) * 4];
            float4 y0 = *(const float4*)&sT2[(a * 8 + j) * 4];
            float4 x1 = *(const float4*)&sT1[(i * 8 + a) * 4];
            float4 y1 = *(const float4*)&sT3[(a * 8 + j) * 4];
            const float xk0[4] = {x0.x, x0.y, x0.z, x0.w};
            const float yj0[4] = {y0.x, y0.y, y0.z, y0.w};
            const float xk1[4] = {x1.x, x1.y, x1.z, x1.w};
            const float yj1[4] = {y1.x, y1.y, y1.z, y1.w};
#pragma unroll
            for (int k = 0; k < 4; ++k)
#pragma unroll
                for (int jp = 0; jp < 4; ++jp) {
                    pa[k][jp] = fmaf(xk0[k], yj0[jp], pa[k][jp]);
                    pb[k][jp] = fmaf(xk1[k], yj1[jp], pb[k][jp]);
                }
        }
#pragma unroll
        for (int k = 0; k < 4; ++k)
#pragma unroll
            for (int jp = 0; jp < 4; ++jp) {
                sPA[(k * 4 + jp) * 64 + lane] = pa[k][jp];
                sPB[(k * 4 + jp) * 64 + lane] = pb[k][jp];
            }
    }
    __syncthreads();

    const int h = lane >> 5, r = lane & 31, m = r & 7, j2 = r >> 3;
    float acc2[2][32];
#pragma unroll
    for (int ti = 0; ti < 2; ++ti)
#pragma unroll
        for (int e = 0; e < 32; ++e) acc2[ti][e] = 0.0f;

#pragma unroll 4
    for (int c = 0; c < 16; ++c) {
        float pav[2][4], pbv[8];
#pragma unroll
        for (int ti = 0; ti < 2; ++ti)
#pragma unroll
            for (int ii = 0; ii < 4; ++ii)
                pav[ti][ii] = sPA[c * 64 + (4 * h + ii) * 8 + (4 * ti + j2)];
#pragma unroll
        for (int l = 0; l < 8; ++l) pbv[l] = sPB[c * 64 + l * 8 + m];
#pragma unroll
        for (int ti = 0; ti < 2; ++ti)
#pragma unroll
            for (int ii = 0; ii < 4; ++ii)
#pragma unroll
                for (int l = 0; l < 8; ++l)
                    acc2[ti][8 * ii + l] = fmaf(pav[ti][ii], pbv[l], acc2[ti][8 * ii + l]);
    }

#pragma unroll
    for (int ti = 0; ti < 2; ++ti) {
        unsigned dw[8];
#pragma unroll
        for (int j = 0; j < 8; ++j) {
            float v[4];
#pragma unroll
            for (int s = 0; s < 4; ++s) {
                float wv = acc2[ti][4 * j + s] * 0.0625f;
                if (ti == h && (4 * j + s) == r) wv -= 1.0f;
                v[s] = wv;
            }
            PACK4(dw[j], v[0], v[1], v[2], v[3])
        }
        Mf8[((size_t)(pair * 16 + combo) * 4 + ti * 2 + 0) * 64 + lane] =
            make_uint4(dw[0], dw[1], dw[2], dw[3]);
        Mf8[((size_t)(pair * 16 + combo) * 4 + ti * 2 + 1) * 64 + lane] =
            make_uint4(dw[4], dw[5], dw[6], dw[7]);
    }
}

// ---------- main: 1 wave/b, dual 16-step chains, fully unrolled ----------
__global__ __launch_bounds__(64, 1)
void mpdo_mfmaK2(const int* __restrict__ qn, const uint4* __restrict__ Mf8,
                 float* __restrict__ out) {
    const int b = blockIdx.x;
    const int lane = threadIdx.x;
    __shared__ float sL[64 * 65];
    const int* qb = qn + (size_t)b * (2 * NSITES);
    const int pi = lane & 31;
    const int pc = (qb[2 * pi] << 3) | (qb[64 + 2 * pi] << 2) |
                   (qb[2 * pi + 1] << 1) | (qb[64 + 2 * pi + 1]);
    const unsigned long long m3 = __ballot(pc & 8);
    const unsigned long long m2 = __ballot(pc & 4);
    const unsigned long long m1 = __ballot(pc & 2);
    const unsigned long long m0 = __ballot(pc & 1);
    const int col = lane & 31, hh = lane >> 5;
    const int laneoff = lane * 16;

    f32x16 acc0[2][2], acc1[2][2];   // chain0: pairs 0..15, chain1: 16..31
#pragma unroll
    for (int rt = 0; rt < 2; ++rt)
#pragma unroll
        for (int ct = 0; ct < 2; ++ct)
#pragma unroll
            for (int g = 0; g < 16; ++g) {
                int row = (g & 3) + 8 * (g >> 2) + 4 * hh;
                float v = (rt == ct && row == col) ? 1.0f : 0.0f;
                acc0[rt][ct][g] = v;
                acc1[rt][ct][g] = v;
            }

    const char* Mbase = (const char*)Mf8;
    AFrag A0[2], A1[2], A2[2];   // chain0 rotation
    AFrag C0[2], C1[2], C2[2];   // chain1 rotation

#define COMBO(T_) ((int)(((((m3) >> (T_)) & 1ull) << 3) | ((((m2) >> (T_)) & 1ull) << 2) | \
                         ((((m1) >> (T_)) & 1ull) << 1) | (((m0) >> (T_)) & 1ull)))
#define LOADF(DST, PIDX)                                                       \
    {                                                                          \
        int c_ = COMBO(PIDX);                                                  \
        const char* nb_ = Mbase + (((size_t)(PIDX) * 16 + c_) << 12) + laneoff;\
        DST[0].q[0] = *(const uint4*)(nb_ + 0 * 1024);                         \
        DST[0].q[1] = *(const uint4*)(nb_ + 1 * 1024);                         \
        DST[1].q[0] = *(const uint4*)(nb_ + 2 * 1024);                         \
        DST[1].q[1] = *(const uint4*)(nb_ + 3 * 1024);                         \
    }

#define MAKE_BCOL(BV, ACC, CT)                                                 \
    {                                                                          \
        _Pragma("unroll")                                                      \
        for (int q = 0; q < 4; ++q) {                                          \
            unsigned p0, p1;                                                   \
            PACK4(p0, ACC[0][CT][4 * q + 0], ACC[0][CT][4 * q + 1],            \
                      ACC[0][CT][4 * q + 2], ACC[0][CT][4 * q + 3])            \
            PACK4(p1, ACC[1][CT][4 * q + 0], ACC[1][CT][4 * q + 1],            \
                      ACC[1][CT][4 * q + 2], ACC[1][CT][4 * q + 3])            \
            asm("v_permlane32_swap_b32 %0, %1" : "+v"(p0), "+v"(p1));          \
            BV[2 * q] = (int)p0; BV[2 * q + 1] = (int)p1;                      \
        }                                                                      \
    }

// one fp8-delta step: ACC <- ACC + D^T ACC; prefetch pair T_+2 if < LIM_
#define STEP1(T_, LIM_, ACC, CUR, NXT)                                         \
    {                                                                          \
        if ((T_) + 2 < (LIM_)) { LOADF(NXT, (T_) + 2) }                        \
        i32x8 b0, b1;                                                          \
        MAKE_BCOL(b0, ACC, 0)                                                  \
        MAKE_BCOL(b1, ACC, 1)                                                  \
        ACC[0][0] = MFMA64(CUR[0].v, b0, ACC[0][0]);                           \
        ACC[0][1] = MFMA64(CUR[0].v, b1, ACC[0][1]);                           \
        ACC[1][0] = MFMA64(CUR[1].v, b0, ACC[1][0]);                           \
        ACC[1][1] = MFMA64(CUR[1].v, b1, ACC[1][1]);                           \
    }

// one interleaved iteration: chain0 step I_, chain1 step 16+I_
#define DSTEP(I_, X, XN, Y, YN)                                                \
    STEP1((I_),      16, acc0, X, XN)                                          \
    STEP1(16 + (I_), 32, acc1, Y, YN)

    LOADF(A0, 0)  LOADF(A1, 1)
    LOADF(C0, 16) LOADF(C1, 17)

    DSTEP(0,  A0, A2, C0, C2) DSTEP(1,  A1, A0, C1, C0) DSTEP(2,  A2, A1, C2, C1)
    DSTEP(3,  A0, A2, C0, C2) DSTEP(4,  A1, A0, C1, C0) DSTEP(5,  A2, A1, C2, C1)
    DSTEP(6,  A0, A2, C0, C2) DSTEP(7,  A1, A0, C1, C0) DSTEP(8,  A2, A1, C2, C1)
    DSTEP(9,  A0, A2, C0, C2) DSTEP(10, A1, A0, C1, C0) DSTEP(11, A2, A1, C2, C1)
    DSTEP(12, A0, A2, C0, C2) DSTEP(13, A1, A0, C1, C0) DSTEP(14, A2, A1, C2, C1)
    DSTEP(15, A0, A2, C0, C2)
#undef DSTEP
#undef STEP1
#undef MAKE_BCOL
#undef LOADF
#undef COMBO

    // ---- same-wave exchange (R13-verified):
    // tr(G0 G1) = sum_{p,q} G0^T[p,q] * G1^T[q,p]
#pragma unroll
    for (int rt = 0; rt < 2; ++rt)
#pragma unroll
        for (int ct = 0; ct < 2; ++ct)
#pragma unroll
            for (int g = 0; g < 16; ++g) {
                int p = 32 * rt + (g & 3) + 8 * (g >> 2) + 4 * hh;
                int q = 32 * ct + col;
                sL[p * 65 + q] = acc1[rt][ct][g];
            }
    __syncthreads();
    {
        float dot = 0.0f;
#pragma unroll
        for (int rt = 0; rt < 2; ++rt)
#pragma unroll
            for (int ct = 0; ct < 2; ++ct)
#pragma unroll
                for (int g = 0; g < 16; ++g) {
                    int p = 32 * rt + (g & 3) + 8 * (g >> 2) + 4 * hh;
                    int q = 32 * ct + col;
                    dot = fmaf(acc0[rt][ct][g], sL[q * 65 + p], dot);
                }
#pragma unroll
        for (int off = 32; off >= 1; off >>= 1)
            dot += __shfl_xor(dot, off, 64);
        if (lane == 0) {
            float tr = dot;
            float re = logf(fabsf(tr)) + 64.0f * 1.3862943611198906f; // undo 4^-64
            float im = (tr < 0.0f) ? 3.14159265358979323846f : 0.0f;
            out[2 * b]     = re;
            out[2 * b + 1] = im;
        }
    }
}

// ---------- fallback fp32 VALU kernel (verified R2) ----------
#define DD 8
#define KCHI 4
__global__ __launch_bounds__(64, 1)
void mpdo_chain(const int* __restrict__ qn, const float* __restrict__ T,
                float* __restrict__ out) {
    const int b = blockIdx.x;
    const int lane = threadIdx.x;
    __shared__ float sA[KCHI][DD][DD];
    __shared__ float sB[KCHI][DD][DD];
    float E[DD][DD];
#pragma unroll
    for (int i = 0; i < DD; ++i)
#pragma unroll
        for (int l = 0; l < DD; ++l) E[i][l] = (i * DD + l == lane) ? 1.0f : 0.0f;
    const int* qb = qn + (size_t)b * (2 * NSITES);
    int ir0 = qb[0], ic0 = qb[NSITES];
    float4 aP = *reinterpret_cast<const float4*>(T + (size_t)ir0 * 256 + lane * 4);
    float4 bP = *reinterpret_cast<const float4*>(T + (size_t)ic0 * 256 + lane * 4);
    const int li = lane >> 3, lj = lane & 7;
#pragma unroll 1
    for (int site = 0; site < NSITES; ++site) {
        __syncthreads();
        sA[0][li][lj] = 0.5f * aP.x; sA[1][li][lj] = 0.5f * aP.y;
        sA[2][li][lj] = 0.5f * aP.z; sA[3][li][lj] = 0.5f * aP.w;
        sB[0][li][lj] = 0.5f * bP.x; sB[1][li][lj] = 0.5f * bP.y;
        sB[2][li][lj] = 0.5f * bP.z; sB[3][li][lj] = 0.5f * bP.w;
        __syncthreads();
        if (site + 1 < NSITES) {
            int irn = qb[site + 1], icn = qb[NSITES + site + 1];
            aP = *reinterpret_cast<const float4*>(T + ((size_t)(site + 1) * 2 + irn) * 256 + lane * 4);
            bP = *reinterpret_cast<const float4*>(T + ((size_t)(site + 1) * 2 + icn) * 256 + lane * 4);
        }
        float Ep[DD][DD];
#pragma unroll
        for (int j = 0; j < DD; ++j)
#pragma unroll
            for (int m = 0; m < DD; ++m) Ep[j][m] = 0.0f;
#pragma unroll 1
        for (int k = 0; k < KCHI; ++k) {
            float tmp[DD][DD];
#pragma unroll
            for (int l = 0; l < DD; ++l) {
                const float4* bp = reinterpret_cast<const float4*>(&sB[k][l][0]);
                float4 b0 = bp[0], b1 = bp[1];
                float brow[DD] = {b0.x, b0.y, b0.z, b0.w, b1.x, b1.y, b1.z, b1.w};
                if (l == 0) {
#pragma unroll
                    for (int i = 0; i < DD; ++i)
#pragma unroll
                        for (int m = 0; m < DD; ++m) tmp[i][m] = E[i][0] * brow[m];
                } else {
#pragma unroll
                    for (int i = 0; i < DD; ++i)
#pragma unroll
                        for (int m = 0; m < DD; ++m)
                            tmp[i][m] = fmaf(E[i][l], brow[m], tmp[i][m]);
                }
            }
#pragma unroll
            for (int i = 0; i < DD; ++i) {
                const float4* ap = reinterpret_cast<const float4*>(&sA[k][i][0]);
                float4 a0 = ap[0], a1 = ap[1];
                float arow[DD] = {a0.x, a0.y, a0.z, a0.w, a1.x, a1.y, a1.z, a1.w};
#pragma unroll
                for (int j = 0; j < DD; ++j)
#pragma unroll
                    for (int m = 0; m < DD; ++m)
                        Ep[j][m] = fmaf(arow[j], tmp[i][m], Ep[j][m]);
            }
        }
#pragma unroll
        for (int i = 0; i < DD; ++i)
#pragma unroll
            for (int l = 0; l < DD; ++l) E[i][l] = Ep[i][l];
    }
    float diag = 0.0f;
#pragma unroll
    for (int i = 0; i < DD; ++i)
#pragma unroll
        for (int l = 0; l < DD; ++l) diag += (i * DD + l == lane) ? E[i][l] : 0.0f;
#pragma unroll
    for (int off = 32; off >= 1; off >>= 1) diag += __shfl_xor(diag, off, 64);
    if (lane == 0) {
        float tr = diag;
        out[2 * b]     = logf(fabsf(tr)) + 64.0f * 1.3862943611198906f;
        out[2 * b + 1] = (tr < 0.0f) ? 3.14159265358979323846f : 0.0f;
    }
}

extern "C" void kernel_launch(void* const* d_in, const int* in_sizes, int n_in,
                              void* d_out, int out_size, void* d_ws, size_t ws_size,
                              hipStream_t stream) {
    const int*   qn  = (const int*)d_in[0];
    const float* T   = (const float*)d_in[1];
    float*       out = (float*)d_out;
    const int B = in_sizes[0] / (2 * NSITES);
    const size_t WS_F8 = (size_t)NPAIRS * 16 * 4 * 64 * 16;  // 2 MB
    if (ws_size >= WS_F8) {
        uint4* Mf8 = (uint4*)d_ws;
        mpdo_prep2f8k<<<dim3(NPAIRS * 16), dim3(64), 0, stream>>>(T, Mf8);
        mpdo_mfmaK2<<<dim3(B), dim3(64), 0, stream>>>(qn, Mf8, out);
    } else {
        mpdo_chain<<<dim3(B), dim3(64), 0, stream>>>(qn, T, out);
    }
}

// Round 19
// 25.469 us; speedup vs baseline: 1.3002x; 1.0127x over previous
//
#include <hip/hip_runtime.h>
#include <math.h>

// MPDO chain: fp8 DELTA pair table + K=64 scaled MFMA, 2 waves/b half-chains.
//   per b: edge = Pi_t M_t (64x64); out = log(tr(edge))
//
// R18 RETRY: R18's NaN is attributed to __launch_bounds__(128,2)'s 256-VGPR
// cap forcing accumulator spills in the unrolled region (R17 identical math
// passed at (64,1) = 512 cap). Changes: (1) __launch_bounds__(128) - no cap;
// (2) symmetric R12-style exchange (both waves write sL[w] unconditionally,
// wave0 reads sL[1]) - no divergent-store predicate.
// Structure: block=128, wave w runs pairs 16w..16w+15 (16 slim K=64 steps,
// fully unrolled, depth-2 rotation); 2048 waves = 2 waves/SIMD to let the
// matrix pipe pipeline ACROSS waves.
// fp8-delta step (R11/R15): X <- X + D^T X, D = (1/16)P - I e4m3; identity
// exact in f32 C-operand. Scale 4^-64 -> log += 64*ln4.
// Fallback: ws < 2MB -> verified fp32 VALU kernel.

#define NSITES 64
#define NPAIRS 32

typedef float f32x16 __attribute__((ext_vector_type(16)));
typedef int   i32x8  __attribute__((ext_vector_type(8)));

union AFrag { uint4 q[2]; i32x8 v; };

// pack 4 f32 -> 1 dword of 4 fp8 e4m3
#define PACK4(P, A0, A1, A2, A3)                                               \
    asm("v_cvt_pk_fp8_f32 %0, %1, %2" : "=v"(P) : "v"(A0), "v"(A1));           \
    asm("v_cvt_pk_fp8_f32 %0, %1, %2 op_sel:[0,0,1]" : "+v"(P) : "v"(A2), "v"(A3));

#define MFMA64(A, B, C)                                                        \
    __builtin_amdgcn_mfma_scale_f32_32x32x64_f8f6f4(                           \
        (A), (B), (C), 0, 0, 0, 0x7F7F7F7F, 0, 0x7F7F7F7F)

// ---------- prep2f8k: D^T = (1/16)P^T - I in fp8, K=64 A-frag (R15-verified) ----------
__global__ __launch_bounds__(64)
void mpdo_prep2f8k(const float* __restrict__ T, uint4* __restrict__ Mf8) {
    const int blk = blockIdx.x;              // 32 pairs * 16 combos
    const int pair = blk >> 4, combo = blk & 15;
    const int c0 = combo >> 2, c1 = combo & 3;
    const int ir0 = c0 >> 1, ic0 = c0 & 1, ir1 = c1 >> 1, ic1 = c1 & 1;
    const int lane = threadIdx.x;
    const int site0 = 2 * pair, site1 = 2 * pair + 1;

    __shared__ float sT0[256], sT1[256], sT2[256], sT3[256];
    __shared__ float sPA[16 * 64], sPB[16 * 64];

    *(float4*)&sT0[lane * 4] = *(const float4*)(T + ((size_t)(site0 * 2 + ir0)) * 256 + lane * 4);
    *(float4*)&sT1[lane * 4] = *(const float4*)(T + ((size_t)(site0 * 2 + ic0)) * 256 + lane * 4);
    *(float4*)&sT2[lane * 4] = *(const float4*)(T + ((size_t)(site1 * 2 + ir1)) * 256 + lane * 4);
    *(float4*)&sT3[lane * 4] = *(const float4*)(T + ((size_t)(site1 * 2 + ic1)) * 256 + lane * 4);
    __syncthreads();

    {
        const int i = lane >> 3, j = lane & 7;
        float pa[4][4], pb[4][4];
#pragma unroll
        for (int k = 0; k < 4; ++k)
#pragma unroll
            for (int jp = 0; jp < 4; ++jp) { pa[k][jp] = 0.0f; pb[k][jp] = 0.0f; }
#pragma unroll
        for (int a = 0; a < 8; ++a) {
            float4 x0 = *(const float4*)&sT0[(i * 8 + a) * 4];
            float4 y0 = *(const float4*)&sT2[(a * 8 + j) * 4];
            float4 x1 = *(const float4*)&sT1[(i * 8 + a) * 4];
            float4 y1 = *(const float4*)&sT3[(a * 8 + j) * 4];
            const float xk0[4] = {x0.x, x0.y, x0.z, x0.w};
            const float yj0[4] = {y0.x, y0.y, y0.z, y0.w};
            const float xk1[4] = {x1.x, x1.y, x1.z, x1.w};
            const float yj1[4] = {y1.x, y1.y, y1.z, y1.w};
#pragma unroll
            for (int k = 0; k < 4; ++k)
#pragma unroll
                for (int jp = 0; jp < 4; ++jp) {
                    pa[k][jp] = fmaf(xk0[k], yj0[jp], pa[k][jp]);
                    pb[k][jp] = fmaf(xk1[k], yj1[jp], pb[k][jp]);
                }
        }
#pragma unroll
        for (int k = 0; k < 4; ++k)
#pragma unroll
            for (int jp = 0; jp < 4; ++jp) {
                sPA[(k * 4 + jp) * 64 + lane] = pa[k][jp];
                sPB[(k * 4 + jp) * 64 + lane] = pb[k][jp];
            }
    }
    __syncthreads();

    const int h = lane >> 5, r = lane & 31, m = r & 7, j2 = r >> 3;
    float acc2[2][32];
#pragma unroll
    for (int ti = 0; ti < 2; ++ti)
#pragma unroll
        for (int e = 0; e < 32; ++e) acc2[ti][e] = 0.0f;

#pragma unroll 4
    for (int c = 0; c < 16; ++c) {
        float pav[2][4], pbv[8];
#pragma unroll
        for (int ti = 0; ti < 2; ++ti)
#pragma unroll
            for (int ii = 0; ii < 4; ++ii)
                pav[ti][ii] = sPA[c * 64 + (4 * h + ii) * 8 + (4 * ti + j2)];
#pragma unroll
        for (int l = 0; l < 8; ++l) pbv[l] = sPB[c * 64 + l * 8 + m];
#pragma unroll
        for (int ti = 0; ti < 2; ++ti)
#pragma unroll
            for (int ii = 0; ii < 4; ++ii)
#pragma unroll
                for (int l = 0; l < 8; ++l)
                    acc2[ti][8 * ii + l] = fmaf(pav[ti][ii], pbv[l], acc2[ti][8 * ii + l]);
    }

#pragma unroll
    for (int ti = 0; ti < 2; ++ti) {
        unsigned dw[8];
#pragma unroll
        for (int j = 0; j < 8; ++j) {
            float v[4];
#pragma unroll
            for (int s = 0; s < 4; ++s) {
                float wv = acc2[ti][4 * j + s] * 0.0625f;
                if (ti == h && (4 * j + s) == r) wv -= 1.0f;
                v[s] = wv;
            }
            PACK4(dw[j], v[0], v[1], v[2], v[3])
        }
        Mf8[((size_t)(pair * 16 + combo) * 4 + ti * 2 + 0) * 64 + lane] =
            make_uint4(dw[0], dw[1], dw[2], dw[3]);
        Mf8[((size_t)(pair * 16 + combo) * 4 + ti * 2 + 1) * 64 + lane] =
            make_uint4(dw[4], dw[5], dw[6], dw[7]);
    }
}

// ---------- main: 2 waves/b (one half-chain each), 16 steps unrolled ----------
__global__ __launch_bounds__(128)
void mpdo_mfmaW2(const int* __restrict__ qn, const uint4* __restrict__ Mf8,
                 float* __restrict__ out) {
    const int b = blockIdx.x;
    const int w = threadIdx.x >> 6;       // half-chain index
    const int lane = threadIdx.x & 63;
    __shared__ float sL[2][64 * 65];
    const int* qb = qn + (size_t)b * (2 * NSITES);
    const int pi = lane & 31;
    const int pc = (qb[2 * pi] << 3) | (qb[64 + 2 * pi] << 2) |
                   (qb[2 * pi + 1] << 1) | (qb[64 + 2 * pi + 1]);
    const unsigned long long m3 = __ballot(pc & 8);
    const unsigned long long m2 = __ballot(pc & 4);
    const unsigned long long m1 = __ballot(pc & 2);
    const unsigned long long m0 = __ballot(pc & 1);
    const int col = lane & 31, hh = lane >> 5;
    const int laneoff = lane * 16;
    const int s0 = 16 * w;                // this wave's pair range [s0, s0+16)

    f32x16 acc[2][2];                     // X = G_w^T, C-layout
#pragma unroll
    for (int rt = 0; rt < 2; ++rt)
#pragma unroll
        for (int ct = 0; ct < 2; ++ct)
#pragma unroll
            for (int g = 0; g < 16; ++g) {
                int row = (g & 3) + 8 * (g >> 2) + 4 * hh;
                acc[rt][ct][g] = (rt == ct && row == col) ? 1.0f : 0.0f;
            }

    const char* Mbase = (const char*)Mf8;
    AFrag A0[2], A1[2], A2[2];

#define COMBO(T_) ((int)(((((m3) >> (T_)) & 1ull) << 3) | ((((m2) >> (T_)) & 1ull) << 2) | \
                         ((((m1) >> (T_)) & 1ull) << 1) | (((m0) >> (T_)) & 1ull)))
#define LOADF(DST, PIDX)                                                       \
    {                                                                          \
        int p_ = (PIDX);                                                       \
        int c_ = COMBO(p_);                                                    \
        const char* nb_ = Mbase + (((size_t)p_ * 16 + c_) << 12) + laneoff;    \
        DST[0].q[0] = *(const uint4*)(nb_ + 0 * 1024);                         \
        DST[0].q[1] = *(const uint4*)(nb_ + 1 * 1024);                         \
        DST[1].q[0] = *(const uint4*)(nb_ + 2 * 1024);                         \
        DST[1].q[1] = *(const uint4*)(nb_ + 3 * 1024);                         \
    }

#define MAKE_BCOL(BV, CT)                                                      \
    {                                                                          \
        _Pragma("unroll")                                                      \
        for (int q = 0; q < 4; ++q) {                                          \
            unsigned p0, p1;                                                   \
            PACK4(p0, acc[0][CT][4 * q + 0], acc[0][CT][4 * q + 1],            \
                      acc[0][CT][4 * q + 2], acc[0][CT][4 * q + 3])            \
            PACK4(p1, acc[1][CT][4 * q + 0], acc[1][CT][4 * q + 1],            \
                      acc[1][CT][4 * q + 2], acc[1][CT][4 * q + 3])            \
            asm("v_permlane32_swap_b32 %0, %1" : "+v"(p0), "+v"(p1));          \
            BV[2 * q] = (int)p0; BV[2 * q + 1] = (int)p1;                      \
        }                                                                      \
    }

// step I_ (0..15) of this wave's half-chain; prefetch I_+2
#define SITE_BODY(I_, CUR, NXT)                                                \
    {                                                                          \
        if ((I_) + 2 < 16) { LOADF(NXT, s0 + (I_) + 2) }                       \
        i32x8 b0, b1;                                                          \
        MAKE_BCOL(b0, 0)                                                       \
        MAKE_BCOL(b1, 1)                                                       \
        acc[0][0] = MFMA64(CUR[0].v, b0, acc[0][0]);                           \
        acc[0][1] = MFMA64(CUR[0].v, b1, acc[0][1]);                           \
        acc[1][0] = MFMA64(CUR[1].v, b0, acc[1][0]);                           \
        acc[1][1] = MFMA64(CUR[1].v, b1, acc[1][1]);                           \
    }

    LOADF(A0, s0)
    LOADF(A1, s0 + 1)

    SITE_BODY(0,  A0, A2) SITE_BODY(1,  A1, A0) SITE_BODY(2,  A2, A1)
    SITE_BODY(3,  A0, A2) SITE_BODY(4,  A1, A0) SITE_BODY(5,  A2, A1)
    SITE_BODY(6,  A0, A2) SITE_BODY(7,  A1, A0) SITE_BODY(8,  A2, A1)
    SITE_BODY(9,  A0, A2) SITE_BODY(10, A1, A0) SITE_BODY(11, A2, A1)
    SITE_BODY(12, A0, A2) SITE_BODY(13, A1, A0) SITE_BODY(14, A2, A1)
    SITE_BODY(15, A0, A2)
#undef SITE_BODY
#undef MAKE_BCOL
#undef LOADF
#undef COMBO

    // ---- symmetric cross-wave exchange (R12-pattern):
    // both waves write their G_w^T to sL[w]; wave0 dots vs sL[1].
#pragma unroll
    for (int rt = 0; rt < 2; ++rt)
#pragma unroll
        for (int ct = 0; ct < 2; ++ct)
#pragma unroll
            for (int g = 0; g < 16; ++g) {
                int p = 32 * rt + (g & 3) + 8 * (g >> 2) + 4 * hh;
                int q = 32 * ct + col;
                sL[w][p * 65 + q] = acc[rt][ct][g];
            }
    __syncthreads();
    if (w == 0) {
        float dot = 0.0f;
#pragma unroll
        for (int rt = 0; rt < 2; ++rt)
#pragma unroll
            for (int ct = 0; ct < 2; ++ct)
#pragma unroll
                for (int g = 0; g < 16; ++g) {
                    int p = 32 * rt + (g & 3) + 8 * (g >> 2) + 4 * hh;
                    int q = 32 * ct + col;
                    dot = fmaf(acc[rt][ct][g], sL[1][q * 65 + p], dot);
                }
#pragma unroll
        for (int off = 32; off >= 1; off >>= 1)
            dot += __shfl_xor(dot, off, 64);
        if (lane == 0) {
            float tr = dot;
            float re = logf(fabsf(tr)) + 64.0f * 1.3862943611198906f; // undo 4^-64
            float im = (tr < 0.0f) ? 3.14159265358979323846f : 0.0f;
            out[2 * b]     = re;
            out[2 * b + 1] = im;
        }
    }
}

// ---------- fallback fp32 VALU kernel (verified R2) ----------
#define DD 8
#define KCHI 4
__global__ __launch_bounds__(64, 1)
void mpdo_chain(const int* __restrict__ qn, const float* __restrict__ T,
                float* __restrict__ out) {
    const int b = blockIdx.x;
    const int lane = threadIdx.x;
    __shared__ float sA[KCHI][DD][DD];
    __shared__ float sB[KCHI][DD][DD];
    float E[DD][DD];
#pragma unroll
    for (int i = 0; i < DD; ++i)
#pragma unroll
        for (int l = 0; l < DD; ++l) E[i][l] = (i * DD + l == lane) ? 1.0f : 0.0f;
    const int* qb = qn + (size_t)b * (2 * NSITES);
    int ir0 = qb[0], ic0 = qb[NSITES];
    float4 aP = *reinterpret_cast<const float4*>(T + (size_t)ir0 * 256 + lane * 4);
    float4 bP = *reinterpret_cast<const float4*>(T + (size_t)ic0 * 256 + lane * 4);
    const int li = lane >> 3, lj = lane & 7;
#pragma unroll 1
    for (int site = 0; site < NSITES; ++site) {
        __syncthreads();
        sA[0][li][lj] = 0.5f * aP.x; sA[1][li][lj] = 0.5f * aP.y;
        sA[2][li][lj] = 0.5f * aP.z; sA[3][li][lj] = 0.5f * aP.w;
        sB[0][li][lj] = 0.5f * bP.x; sB[1][li][lj] = 0.5f * bP.y;
        sB[2][li][lj] = 0.5f * bP.z; sB[3][li][lj] = 0.5f * bP.w;
        __syncthreads();
        if (site + 1 < NSITES) {
            int irn = qb[site + 1], icn = qb[NSITES + site + 1];
            aP = *reinterpret_cast<const float4*>(T + ((size_t)(site + 1) * 2 + irn) * 256 + lane * 4);
            bP = *reinterpret_cast<const float4*>(T + ((size_t)(site + 1) * 2 + icn) * 256 + lane * 4);
        }
        float Ep[DD][DD];
#pragma unroll
        for (int j = 0; j < DD; ++j)
#pragma unroll
            for (int m = 0; m < DD; ++m) Ep[j][m] = 0.0f;
#pragma unroll 1
        for (int k = 0; k < KCHI; ++k) {
            float tmp[DD][DD];
#pragma unroll
            for (int l = 0; l < DD; ++l) {
                const float4* bp = reinterpret_cast<const float4*>(&sB[k][l][0]);
                float4 b0 = bp[0], b1 = bp[1];
                float brow[DD] = {b0.x, b0.y, b0.z, b0.w, b1.x, b1.y, b1.z, b1.w};
                if (l == 0) {
#pragma unroll
                    for (int i = 0; i < DD; ++i)
#pragma unroll
                        for (int m = 0; m < DD; ++m) tmp[i][m] = E[i][0] * brow[m];
                } else {
#pragma unroll
                    for (int i = 0; i < DD; ++i)
#pragma unroll
                        for (int m = 0; m < DD; ++m)
                            tmp[i][m] = fmaf(E[i][l], brow[m], tmp[i][m]);
                }
            }
#pragma unroll
            for (int i = 0; i < DD; ++i) {
                const float4* ap = reinterpret_cast<const float4*>(&sA[k][i][0]);
                float4 a0 = ap[0], a1 = ap[1];
                float arow[DD] = {a0.x, a0.y, a0.z, a0.w, a1.x, a1.y, a1.z, a1.w};
#pragma unroll
                for (int j = 0; j < DD; ++j)
#pragma unroll
                    for (int m = 0; m < DD; ++m)
                        Ep[j][m] = fmaf(arow[j], tmp[i][m], Ep[j][m]);
            }
        }
#pragma unroll
        for (int i = 0; i < DD; ++i)
#pragma unroll
            for (int l = 0; l < DD; ++l) E[i][l] = Ep[i][l];
    }
    float diag = 0.0f;
#pragma unroll
    for (int i = 0; i < DD; ++i)
#pragma unroll
        for (int l = 0; l < DD; ++l) diag += (i * DD + l == lane) ? E[i][l] : 0.0f;
#pragma unroll
    for (int off = 32; off >= 1; off >>= 1) diag += __shfl_xor(diag, off, 64);
    if (lane == 0) {
        float tr = diag;
        out[2 * b]     = logf(fabsf(tr)) + 64.0f * 1.3862943611198906f;
        out[2 * b + 1] = (tr < 0.0f) ? 3.14159265358979323846f : 0.0f;
    }
}

extern "C" void kernel_launch(void* const* d_in, const int* in_sizes, int n_in,
                              void* d_out, int out_size, void* d_ws, size_t ws_size,
                              hipStream_t stream) {
    const int*   qn  = (const int*)d_in[0];
    const float* T   = (const float*)d_in[1];
    float*       out = (float*)d_out;
    const int B = in_sizes[0] / (2 * NSITES);
    const size_t WS_F8 = (size_t)NPAIRS * 16 * 4 * 64 * 16;  // 2 MB
    if (ws_size >= WS_F8) {
        uint4* Mf8 = (uint4*)d_ws;
        mpdo_prep2f8k<<<dim3(NPAIRS * 16), dim3(64), 0, stream>>>(T, Mf8);
        mpdo_mfmaW2<<<dim3(B), dim3(128), 0, stream>>>(qn, Mf8, out);
    } else {
        mpdo_chain<<<dim3(B), dim3(64), 0, stream>>>(qn, T, out);
    }
}